// Round 1
// baseline (3700.095 us; speedup 1.0000x reference)
//
#include <hip/hip_runtime.h>

#define H 64
#define DEF 256  // edge feature dim

// ---------------- node init: out[row] = mlp2(emb[n_id[row]]) -------------
__global__ __launch_bounds__(256) void node_init_kernel(
    const float* __restrict__ emb, const int* __restrict__ n_id, int N,
    const float* __restrict__ W1, const float* __restrict__ b1,
    const float* __restrict__ W2, const float* __restrict__ b2,
    float* __restrict__ out)
{
    __shared__ float sW1[H*H], sW2[H*H], sb1[H], sb2[H];
    __shared__ float sx[4][H], sh[4][H];
    const int tid = threadIdx.x;
    for (int i = tid; i < H*H; i += 256) { sW1[i] = W1[i]; sW2[i] = W2[i]; }
    if (tid < H) { sb1[tid] = b1[tid]; sb2[tid] = b2[tid]; }
    __syncthreads();
    const int r = tid >> 6, c = tid & 63;
    for (int base = blockIdx.x * 4; base < N; base += gridDim.x * 4) {
        const int row = base + r;
        const bool ok = row < N;
        if (ok) sx[r][c] = emb[(size_t)n_id[row] * H + c];
        __syncthreads();
        float acc = sb1[c];
        if (ok) {
#pragma unroll
            for (int k = 0; k < H; ++k) acc = fmaf(sx[r][k], sW1[k*H + c], acc);
        }
        sh[r][c] = fmaxf(acc, 0.f);
        __syncthreads();
        if (ok) {
            float acc2 = sb2[c];
#pragma unroll
            for (int k = 0; k < H; ++k) acc2 = fmaf(sh[r][k], sW2[k*H + c], acc2);
            out[(size_t)row * H + c] = acc2;
        }
        __syncthreads();
    }
}

// ------------- edge init: out[e] = mlp2(edge_attr[e])  (256 -> 64 -> 64) ----
__global__ __launch_bounds__(512) void edge_init_kernel(
    const float* __restrict__ attr, int E_,
    const float* __restrict__ W1, const float* __restrict__ b1,
    const float* __restrict__ W2, const float* __restrict__ b2,
    float* __restrict__ out)
{
    __shared__ float sW1[DEF*H];      // 64 KB
    __shared__ float sW2[H*H];        // 16 KB
    __shared__ float sb1[H], sb2[H];
    __shared__ float sx[8][DEF];      // 8 KB
    __shared__ float sh[8][H];        // 2 KB
    const int tid = threadIdx.x;
    for (int i = tid; i < DEF*H; i += 512) sW1[i] = W1[i];
    for (int i = tid; i < H*H; i += 512) sW2[i] = W2[i];
    if (tid < H) { sb1[tid] = b1[tid]; sb2[tid] = b2[tid]; }
    __syncthreads();
    const int r = tid >> 6, c = tid & 63;
    for (int base = blockIdx.x * 8; base < E_; base += gridDim.x * 8) {
        const int row = base + r;
        const bool ok = row < E_;
        if (ok) {
#pragma unroll
            for (int j = 0; j < 4; ++j)
                sx[r][c + j*64] = attr[(size_t)row * DEF + c + j*64];
        }
        __syncthreads();
        float acc = sb1[c];
        if (ok) {
#pragma unroll 8
            for (int k = 0; k < DEF; ++k) acc = fmaf(sx[r][k], sW1[k*H + c], acc);
        }
        sh[r][c] = fmaxf(acc, 0.f);
        __syncthreads();
        if (ok) {
            float acc2 = sb2[c];
#pragma unroll
            for (int k = 0; k < H; ++k) acc2 = fmaf(sh[r][k], sW2[k*H + c], acc2);
            out[(size_t)row * H + c] = acc2;
        }
        __syncthreads();
    }
}

// ---- edge message: m = mlp2(cat[featA[idxA], featB[idxB], eFeat[e]]); atomic add at idxOut
__global__ __launch_bounds__(256) void edge_msg_kernel(
    const float* __restrict__ featA, const int* __restrict__ idxA,
    const float* __restrict__ featB, const int* __restrict__ idxB,
    const float* __restrict__ eFeat,
    const int* __restrict__ idxOut, int E_,
    const float* __restrict__ W1, const float* __restrict__ b1,
    const float* __restrict__ W2, const float* __restrict__ b2,
    float* __restrict__ outAcc)
{
    __shared__ float sW1[192*H];   // 48 KB
    __shared__ float sW2[H*H];     // 16 KB
    __shared__ float sb1[H], sb2[H];
    __shared__ float sx[4][192];   // 3 KB
    __shared__ float sh[4][H];     // 1 KB
    const int tid = threadIdx.x;
    for (int i = tid; i < 192*H; i += 256) sW1[i] = W1[i];
    for (int i = tid; i < H*H; i += 256) sW2[i] = W2[i];
    if (tid < H) { sb1[tid] = b1[tid]; sb2[tid] = b2[tid]; }
    __syncthreads();
    const int r = tid >> 6, c = tid & 63;
    for (int base = blockIdx.x * 4; base < E_; base += gridDim.x * 4) {
        const int row = base + r;
        const bool ok = row < E_;
        if (ok) {
            sx[r][c]       = featA[(size_t)idxA[row] * H + c];
            sx[r][64 + c]  = featB[(size_t)idxB[row] * H + c];
            sx[r][128 + c] = eFeat[(size_t)row * H + c];
        }
        __syncthreads();
        float acc = sb1[c];
        if (ok) {
#pragma unroll 8
            for (int k = 0; k < 192; ++k) acc = fmaf(sx[r][k], sW1[k*H + c], acc);
        }
        sh[r][c] = fmaxf(acc, 0.f);
        __syncthreads();
        if (ok) {
            float acc2 = sb2[c];
#pragma unroll
            for (int k = 0; k < H; ++k) acc2 = fmaf(sh[r][k], sW2[k*H + c], acc2);
            unsafeAtomicAdd(&outAcc[(size_t)idxOut[row] * H + c], acc2);
        }
        __syncthreads();
    }
}

// ---------------- conv buffer init: conv = (1+eps)*h --------------------
__global__ void scale_kernel(const float* __restrict__ h, float* __restrict__ conv, size_t n)
{
    const size_t stride = (size_t)gridDim.x * blockDim.x;
    const float4* h4 = (const float4*)h;
    float4* c4 = (float4*)conv;
    for (size_t j = (size_t)blockIdx.x * blockDim.x + threadIdx.x; j < n/4; j += stride) {
        float4 v = h4[j];
        v.x *= 1.1f; v.y *= 1.1f; v.z *= 1.1f; v.w *= 1.1f;
        c4[j] = v;
    }
}

// ---------------- update: h = relu(h + conv)  or  h = conv ------------------
__global__ void update_kernel(float* __restrict__ h, const float* __restrict__ conv,
                              size_t n, int relu_res)
{
    const size_t stride = (size_t)gridDim.x * blockDim.x;
    float4* h4 = (float4*)h;
    const float4* c4 = (const float4*)conv;
    for (size_t j = (size_t)blockIdx.x * blockDim.x + threadIdx.x; j < n/4; j += stride) {
        float4 hv = h4[j];
        float4 cv = c4[j];
        if (relu_res) {
            hv.x = fmaxf(hv.x + cv.x, 0.f);
            hv.y = fmaxf(hv.y + cv.y, 0.f);
            hv.z = fmaxf(hv.z + cv.z, 0.f);
            hv.w = fmaxf(hv.w + cv.w, 0.f);
        } else {
            hv = cv;
        }
        h4[j] = hv;
    }
}

// ---------------- classifier: out = mlp2(cat[hu[i0], hb[i1]]) @ [64,1] ------
__global__ __launch_bounds__(256) void cls_kernel(
    const float* __restrict__ hu, const float* __restrict__ hb,
    const int* __restrict__ i0, const int* __restrict__ i1, int EL_,
    const float* __restrict__ W1, const float* __restrict__ b1,
    const float* __restrict__ W2, const float* __restrict__ b2,
    float* __restrict__ out)
{
    __shared__ float sW1[2*H*H];   // 32 KB
    __shared__ float sW2[H], sb1[H];
    __shared__ float sx[4][2*H];
    const int tid = threadIdx.x;
    for (int i = tid; i < 2*H*H; i += 256) sW1[i] = W1[i];
    if (tid < H) { sW2[tid] = W2[tid]; sb1[tid] = b1[tid]; }
    __syncthreads();
    const float bias2 = b2[0];
    const int r = tid >> 6, c = tid & 63;
    for (int base = blockIdx.x * 4; base < EL_; base += gridDim.x * 4) {
        const int row = base + r;
        const bool ok = row < EL_;
        if (ok) {
            sx[r][c]      = hu[(size_t)i0[row] * H + c];
            sx[r][64 + c] = hb[(size_t)i1[row] * H + c];
        }
        __syncthreads();
        if (ok) {
            float acc = sb1[c];
#pragma unroll
            for (int k = 0; k < 2*H; ++k) acc = fmaf(sx[r][k], sW1[k*H + c], acc);
            float v = fmaxf(acc, 0.f) * sW2[c];
#pragma unroll
            for (int off = 32; off > 0; off >>= 1) v += __shfl_down(v, off);
            if (c == 0) out[row] = v + bias2;
        }
        __syncthreads();
    }
}

extern "C" void kernel_launch(void* const* d_in, const int* in_sizes, int n_in,
                              void* d_out, int out_size, void* d_ws, size_t ws_size,
                              hipStream_t stream)
{
    const float* emb_user = (const float*)d_in[0];
    const float* emb_book = (const float*)d_in[1];
    const float* nu_W1 = (const float*)d_in[2];
    const float* nu_b1 = (const float*)d_in[3];
    const float* nu_W2 = (const float*)d_in[4];
    const float* nu_b2 = (const float*)d_in[5];
    const float* nb_W1 = (const float*)d_in[6];
    const float* nb_b1 = (const float*)d_in[7];
    const float* nb_W2 = (const float*)d_in[8];
    const float* nb_b2 = (const float*)d_in[9];
    const float* eu_W1 = (const float*)d_in[10];
    const float* eu_b1 = (const float*)d_in[11];
    const float* eu_W2 = (const float*)d_in[12];
    const float* eu_b2 = (const float*)d_in[13];
    const float* eb_W1 = (const float*)d_in[14];
    const float* eb_b1 = (const float*)d_in[15];
    const float* eb_W2 = (const float*)d_in[16];
    const float* eb_b2 = (const float*)d_in[17];
    const float* cu2b_W1 = (const float*)d_in[18];
    const float* cu2b_b1 = (const float*)d_in[19];
    const float* cu2b_W2 = (const float*)d_in[20];
    const float* cu2b_b2 = (const float*)d_in[21];
    const float* cb2u_W1 = (const float*)d_in[22];
    const float* cb2u_b1 = (const float*)d_in[23];
    const float* cb2u_W2 = (const float*)d_in[24];
    const float* cb2u_b2 = (const float*)d_in[25];
    const float* cls_W1 = (const float*)d_in[26];
    const float* cls_b1 = (const float*)d_in[27];
    const float* cls_W2 = (const float*)d_in[28];
    const float* cls_b2 = (const float*)d_in[29];
    const float* edge_attr = (const float*)d_in[30];
    const int* n_id_user = (const int*)d_in[31];
    const int* n_id_book = (const int*)d_in[32];
    const int* edge_index = (const int*)d_in[33];
    const int* edge_label_index = (const int*)d_in[34];

    const int NU = in_sizes[31];
    const int NB = in_sizes[32];
    const int E  = in_sizes[33] / 2;
    const int EL = in_sizes[34] / 2;

    const int* src = edge_index;          // user index per edge
    const int* dst = edge_index + E;      // book index per edge
    const int* li0 = edge_label_index;
    const int* li1 = edge_label_index + EL;

    float* ws = (float*)d_ws;
    float* hu = ws;                           // NU*H
    float* hb = hu + (size_t)NU * H;          // NB*H
    float* cu = hb + (size_t)NB * H;          // NU*H
    float* cb = cu + (size_t)NU * H;          // NB*H
    float* eu = cb + (size_t)NB * H;          // E*H
    float* eb = eu + (size_t)E * H;           // E*H

    // node init MLPs
    node_init_kernel<<<2048, 256, 0, stream>>>(emb_user, n_id_user, NU,
        nu_W1, nu_b1, nu_W2, nu_b2, hu);
    node_init_kernel<<<2048, 256, 0, stream>>>(emb_book, n_id_book, NB,
        nb_W1, nb_b1, nb_W2, nb_b2, hb);
    // edge init MLPs
    edge_init_kernel<<<1024, 512, 0, stream>>>(edge_attr, E, eu_W1, eu_b1, eu_W2, eu_b2, eu);
    edge_init_kernel<<<1024, 512, 0, stream>>>(edge_attr, E, eb_W1, eb_b1, eb_W2, eb_b2, eb);

    for (int l = 0; l < 2; ++l) {
        scale_kernel<<<1024, 256, 0, stream>>>(hu, cu, (size_t)NU * H);
        scale_kernel<<<1024, 256, 0, stream>>>(hb, cb, (size_t)NB * H);
        // user -> book: m = nn(cat[hb[dst], hu[src], eu]), scatter at dst into cb
        edge_msg_kernel<<<1024, 256, 0, stream>>>(hb, dst, hu, src, eu, dst, E,
            cu2b_W1 + (size_t)l * 192 * H, cu2b_b1 + l * H,
            cu2b_W2 + (size_t)l * H * H,  cu2b_b2 + l * H, cb);
        // book -> user: m = nn(cat[hu[src], hb[dst], eb]), scatter at src into cu
        edge_msg_kernel<<<1024, 256, 0, stream>>>(hu, src, hb, dst, eb, src, E,
            cb2u_W1 + (size_t)l * 192 * H, cb2u_b1 + l * H,
            cb2u_W2 + (size_t)l * H * H,  cb2u_b2 + l * H, cu);
        update_kernel<<<1024, 256, 0, stream>>>(hu, cu, (size_t)NU * H, l == 0 ? 1 : 0);
        update_kernel<<<1024, 256, 0, stream>>>(hb, cb, (size_t)NB * H, l == 0 ? 1 : 0);
    }

    cls_kernel<<<2048, 256, 0, stream>>>(hu, hb, li0, li1, EL,
        cls_W1, cls_b1, cls_W2, cls_b2, (float*)d_out);
}

// Round 5
// 577.899 us; speedup vs baseline: 6.4027x; 6.4027x over previous
//
// Retry: identical MFMA rewrite — rounds 2-4 never executed (dead container).
#include <hip/hip_runtime.h>

typedef unsigned short u16;
typedef __attribute__((ext_vector_type(8))) short bf16x8;
typedef __attribute__((ext_vector_type(4))) float f32x4;
typedef __attribute__((ext_vector_type(4))) unsigned short u16x4;

#define NMAT 17

__device__ __forceinline__ u16 f2bf(float f) {
    union { float f; unsigned u; } a; a.f = f;
    unsigned u = a.u;
    return (u16)((u + (((u >> 16) & 1u) + 0x7fffu)) >> 16);
}

// ---------------- weight prep: W[K][64] f32 -> Wt[64][K] bf16 ----------------
struct PrepArgs { const float* src[NMAT]; int dstoff[NMAT]; int K[NMAT]; };

__global__ __launch_bounds__(256) void prep_weights(PrepArgs a, u16* __restrict__ pool) {
    int m = blockIdx.x >> 6;
    int idx = (blockIdx.x & 63) * 256 + threadIdx.x;
    int K = a.K[m];
    if (idx < K * 64) {
        int col = idx / K, k = idx - col * K;
        pool[a.dstoff[m] + idx] = f2bf(a.src[m][(size_t)k * 64 + col]);
    }
}

// ---------------- node init: h = mlp2(emb[nid]) ; out f32 + bf16 ------------
__global__ __launch_bounds__(512) void node_init_mfma(
    const float* __restrict__ emb, const int* __restrict__ nid, int N,
    const u16* __restrict__ W1, const float* __restrict__ b1,
    const u16* __restrict__ W2, const float* __restrict__ b2,
    float* __restrict__ hf, u16* __restrict__ hbf)
{
    __shared__ u16 sW1[64 * 72], sW2[64 * 72], sHid[128 * 72];
    const int tid = threadIdx.x;
    const int wv = tid >> 6, lane = tid & 63;
    const int lr = lane & 15, lk = lane >> 4;

    for (int c = tid; c < 512; c += 512) {
        int row = c >> 3, cc = c & 7;
        *(bf16x8*)&sW1[row * 72 + cc * 8] = *(const bf16x8*)&W1[row * 64 + cc * 8];
        *(bf16x8*)&sW2[row * 72 + cc * 8] = *(const bf16x8*)&W2[row * 64 + cc * 8];
    }
    float b1v[4], b2v[4];
#pragma unroll
    for (int n = 0; n < 4; ++n) { b1v[n] = b1[lr + 16 * n]; b2v[n] = b2[lr + 16 * n]; }

    const int nT = (N + 127) >> 7;
    for (int t = blockIdx.x; t < nT; t += gridDim.x) {
        const int rb = t * 128 + wv * 16;
        int ar = rb + lr; if (ar >= N) ar = N - 1;
        const int g = nid[ar];
        const float* ap = emb + (size_t)g * 64 + lk * 8;
        bf16x8 afr[2];
#pragma unroll
        for (int ks = 0; ks < 2; ++ks) {
            f32x4 lo = *(const f32x4*)(ap + ks * 32);
            f32x4 hi = *(const f32x4*)(ap + ks * 32 + 4);
            bf16x8 v;
            v[0] = (short)f2bf(lo[0]); v[1] = (short)f2bf(lo[1]);
            v[2] = (short)f2bf(lo[2]); v[3] = (short)f2bf(lo[3]);
            v[4] = (short)f2bf(hi[0]); v[5] = (short)f2bf(hi[1]);
            v[6] = (short)f2bf(hi[2]); v[7] = (short)f2bf(hi[3]);
            afr[ks] = v;
        }
        __syncthreads();  // initial staging + protect sHid from prev tile's reads
        f32x4 acc[4];
#pragma unroll
        for (int n = 0; n < 4; ++n) acc[n] = (f32x4){b1v[n], b1v[n], b1v[n], b1v[n]};
#pragma unroll
        for (int ks = 0; ks < 2; ++ks) {
#pragma unroll
            for (int n = 0; n < 4; ++n) {
                bf16x8 bfr = *(const bf16x8*)&sW1[(lr + 16 * n) * 72 + ks * 32 + lk * 8];
                acc[n] = __builtin_amdgcn_mfma_f32_16x16x32_bf16(afr[ks], bfr, acc[n], 0, 0, 0);
            }
        }
#pragma unroll
        for (int n = 0; n < 4; ++n)
#pragma unroll
            for (int i = 0; i < 4; ++i)
                sHid[(wv * 16 + lk * 4 + i) * 72 + lr + 16 * n] = f2bf(fmaxf(acc[n][i], 0.f));
        __syncthreads();
        f32x4 a2[4];
#pragma unroll
        for (int n = 0; n < 4; ++n) a2[n] = (f32x4){b2v[n], b2v[n], b2v[n], b2v[n]};
#pragma unroll
        for (int ks = 0; ks < 2; ++ks) {
            bf16x8 af = *(const bf16x8*)&sHid[(wv * 16 + lr) * 72 + ks * 32 + lk * 8];
#pragma unroll
            for (int n = 0; n < 4; ++n) {
                bf16x8 bfr = *(const bf16x8*)&sW2[(lr + 16 * n) * 72 + ks * 32 + lk * 8];
                a2[n] = __builtin_amdgcn_mfma_f32_16x16x32_bf16(af, bfr, a2[n], 0, 0, 0);
            }
        }
#pragma unroll
        for (int i = 0; i < 4; ++i) {
            int r = rb + lk * 4 + i;
            if (r < N) {
#pragma unroll
                for (int n = 0; n < 4; ++n) {
                    hf[(size_t)r * 64 + lr + 16 * n] = a2[n][i];
                    hbf[(size_t)r * 64 + lr + 16 * n] = f2bf(a2[n][i]);
                }
            }
        }
    }
}

// -------- fused edge init: eu = mlp2_u(attr), eb = mlp2_b(attr), attr read once
__global__ __launch_bounds__(512) void edge_init_fused(
    const float* __restrict__ attr, int E_,
    const u16* __restrict__ W1u, const float* __restrict__ b1u,
    const u16* __restrict__ W2u, const float* __restrict__ b2u,
    const u16* __restrict__ W1b, const float* __restrict__ b1b,
    const u16* __restrict__ W2b, const float* __restrict__ b2b,
    u16* __restrict__ eu, u16* __restrict__ eb)
{
    __shared__ u16 sW1[64 * 264];
    __shared__ u16 sW2[2][64 * 72];
    __shared__ u16 sHid[128 * 72];
    const int tid = threadIdx.x;
    const int wv = tid >> 6, lane = tid & 63;
    const int lr = lane & 15, lk = lane >> 4;

    for (int c = tid; c < 512; c += 512) {
        int row = c >> 3, cc = c & 7;
        *(bf16x8*)&sW2[0][row * 72 + cc * 8] = *(const bf16x8*)&W2u[row * 64 + cc * 8];
        *(bf16x8*)&sW2[1][row * 72 + cc * 8] = *(const bf16x8*)&W2b[row * 64 + cc * 8];
    }
    float b1v[2][4], b2v[2][4];
#pragma unroll
    for (int n = 0; n < 4; ++n) {
        b1v[0][n] = b1u[lr + 16 * n]; b1v[1][n] = b1b[lr + 16 * n];
        b2v[0][n] = b2u[lr + 16 * n]; b2v[1][n] = b2b[lr + 16 * n];
    }

    const int nT = (E_ + 127) >> 7;
    for (int t = blockIdx.x; t < nT; t += gridDim.x) {
        const int rb = t * 128 + wv * 16;
        int ar = rb + lr; if (ar >= E_) ar = E_ - 1;
        const float* ap = attr + (size_t)ar * 256 + lk * 8;
        bf16x8 afr[8];
#pragma unroll
        for (int ks = 0; ks < 8; ++ks) {
            f32x4 lo = *(const f32x4*)(ap + ks * 32);
            f32x4 hi = *(const f32x4*)(ap + ks * 32 + 4);
            bf16x8 v;
            v[0] = (short)f2bf(lo[0]); v[1] = (short)f2bf(lo[1]);
            v[2] = (short)f2bf(lo[2]); v[3] = (short)f2bf(lo[3]);
            v[4] = (short)f2bf(hi[0]); v[5] = (short)f2bf(hi[1]);
            v[6] = (short)f2bf(hi[2]); v[7] = (short)f2bf(hi[3]);
            afr[ks] = v;
        }
#pragma unroll
        for (int dir = 0; dir < 2; ++dir) {
            __syncthreads();   // prev use of sW1/sHid complete
            const u16* w1g = dir ? W1b : W1u;
            for (int c = tid; c < 2048; c += 512) {
                int row = c >> 5, cc = c & 31;
                *(bf16x8*)&sW1[row * 264 + cc * 8] = *(const bf16x8*)&w1g[row * 256 + cc * 8];
            }
            __syncthreads();
            f32x4 acc[4];
#pragma unroll
            for (int n = 0; n < 4; ++n) acc[n] = (f32x4){b1v[dir][n], b1v[dir][n], b1v[dir][n], b1v[dir][n]};
#pragma unroll
            for (int ks = 0; ks < 8; ++ks) {
#pragma unroll
                for (int n = 0; n < 4; ++n) {
                    bf16x8 bfr = *(const bf16x8*)&sW1[(lr + 16 * n) * 264 + ks * 32 + lk * 8];
                    acc[n] = __builtin_amdgcn_mfma_f32_16x16x32_bf16(afr[ks], bfr, acc[n], 0, 0, 0);
                }
            }
#pragma unroll
            for (int n = 0; n < 4; ++n)
#pragma unroll
                for (int i = 0; i < 4; ++i)
                    sHid[(wv * 16 + lk * 4 + i) * 72 + lr + 16 * n] = f2bf(fmaxf(acc[n][i], 0.f));
            __syncthreads();
            f32x4 a2[4];
#pragma unroll
            for (int n = 0; n < 4; ++n) a2[n] = (f32x4){b2v[dir][n], b2v[dir][n], b2v[dir][n], b2v[dir][n]};
#pragma unroll
            for (int ks = 0; ks < 2; ++ks) {
                bf16x8 af = *(const bf16x8*)&sHid[(wv * 16 + lr) * 72 + ks * 32 + lk * 8];
#pragma unroll
                for (int n = 0; n < 4; ++n) {
                    bf16x8 bfr = *(const bf16x8*)&sW2[dir][(lr + 16 * n) * 72 + ks * 32 + lk * 8];
                    a2[n] = __builtin_amdgcn_mfma_f32_16x16x32_bf16(af, bfr, a2[n], 0, 0, 0);
                }
            }
            u16* op = dir ? eb : eu;
#pragma unroll
            for (int i = 0; i < 4; ++i) {
                int r = rb + lk * 4 + i;
                if (r < E_) {
#pragma unroll
                    for (int n = 0; n < 4; ++n)
                        op[(size_t)r * 64 + lr + 16 * n] = f2bf(a2[n][i]);
                }
            }
        }
    }
}

// -------- fused edge messages (both directions), atomic scatter-add ---------
__global__ __launch_bounds__(512) void edge_msg_fused(
    const u16* __restrict__ hub, const u16* __restrict__ hbb,
    const int* __restrict__ src, const int* __restrict__ dst,
    const u16* __restrict__ eu, const u16* __restrict__ eb, int E_,
    const u16* __restrict__ W1a, const float* __restrict__ b1a,
    const u16* __restrict__ W2a, const float* __restrict__ b2a,
    const u16* __restrict__ W1b, const float* __restrict__ b1b,
    const u16* __restrict__ W2b, const float* __restrict__ b2b,
    float* __restrict__ cb, float* __restrict__ cu)
{
    __shared__ u16 sW1[64 * 200];
    __shared__ u16 sW2[2][64 * 72];
    __shared__ u16 sHid[128 * 72];
    const int tid = threadIdx.x;
    const int wv = tid >> 6, lane = tid & 63;
    const int lr = lane & 15, lk = lane >> 4;

    for (int c = tid; c < 512; c += 512) {
        int row = c >> 3, cc = c & 7;
        *(bf16x8*)&sW2[0][row * 72 + cc * 8] = *(const bf16x8*)&W2a[row * 64 + cc * 8];
        *(bf16x8*)&sW2[1][row * 72 + cc * 8] = *(const bf16x8*)&W2b[row * 64 + cc * 8];
    }
    float b1v[2][4], b2v[2][4];
#pragma unroll
    for (int n = 0; n < 4; ++n) {
        b1v[0][n] = b1a[lr + 16 * n]; b1v[1][n] = b1b[lr + 16 * n];
        b2v[0][n] = b2a[lr + 16 * n]; b2v[1][n] = b2b[lr + 16 * n];
    }

    const int nT = (E_ + 127) >> 7;
    for (int t = blockIdx.x; t < nT; t += gridDim.x) {
        const int rb = t * 128 + wv * 16;
        int ar = rb + lr; if (ar >= E_) ar = E_ - 1;
        const int is = src[ar], id = dst[ar];
        bf16x8 fb[2], fu[2], fe0[2], fe1[2];
#pragma unroll
        for (int ks = 0; ks < 2; ++ks) {
            fb[ks]  = *(const bf16x8*)&hbb[(size_t)id * 64 + ks * 32 + lk * 8];
            fu[ks]  = *(const bf16x8*)&hub[(size_t)is * 64 + ks * 32 + lk * 8];
            fe0[ks] = *(const bf16x8*)&eu[(size_t)ar * 64 + ks * 32 + lk * 8];
            fe1[ks] = *(const bf16x8*)&eb[(size_t)ar * 64 + ks * 32 + lk * 8];
        }
#pragma unroll
        for (int dir = 0; dir < 2; ++dir) {
            __syncthreads();
            const u16* w1g = dir ? W1b : W1a;
            for (int c = tid; c < 1536; c += 512) {
                int row = c / 24, cc = c - row * 24;
                *(bf16x8*)&sW1[row * 200 + cc * 8] = *(const bf16x8*)&w1g[row * 192 + cc * 8];
            }
            __syncthreads();
            bf16x8 aseq[6];
            if (dir == 0) { aseq[0]=fb[0]; aseq[1]=fb[1]; aseq[2]=fu[0]; aseq[3]=fu[1]; aseq[4]=fe0[0]; aseq[5]=fe0[1]; }
            else          { aseq[0]=fu[0]; aseq[1]=fu[1]; aseq[2]=fb[0]; aseq[3]=fb[1]; aseq[4]=fe1[0]; aseq[5]=fe1[1]; }
            f32x4 acc[4];
#pragma unroll
            for (int n = 0; n < 4; ++n) acc[n] = (f32x4){b1v[dir][n], b1v[dir][n], b1v[dir][n], b1v[dir][n]};
#pragma unroll
            for (int ks = 0; ks < 6; ++ks) {
#pragma unroll
                for (int n = 0; n < 4; ++n) {
                    bf16x8 bfr = *(const bf16x8*)&sW1[(lr + 16 * n) * 200 + ks * 32 + lk * 8];
                    acc[n] = __builtin_amdgcn_mfma_f32_16x16x32_bf16(aseq[ks], bfr, acc[n], 0, 0, 0);
                }
            }
#pragma unroll
            for (int n = 0; n < 4; ++n)
#pragma unroll
                for (int i = 0; i < 4; ++i)
                    sHid[(wv * 16 + lk * 4 + i) * 72 + lr + 16 * n] = f2bf(fmaxf(acc[n][i], 0.f));
            __syncthreads();
            f32x4 a2[4];
#pragma unroll
            for (int n = 0; n < 4; ++n) a2[n] = (f32x4){b2v[dir][n], b2v[dir][n], b2v[dir][n], b2v[dir][n]};
#pragma unroll
            for (int ks = 0; ks < 2; ++ks) {
                bf16x8 af = *(const bf16x8*)&sHid[(wv * 16 + lr) * 72 + ks * 32 + lk * 8];
#pragma unroll
                for (int n = 0; n < 4; ++n) {
                    bf16x8 bfr = *(const bf16x8*)&sW2[dir][(lr + 16 * n) * 72 + ks * 32 + lk * 8];
                    a2[n] = __builtin_amdgcn_mfma_f32_16x16x32_bf16(af, bfr, a2[n], 0, 0, 0);
                }
            }
            float* outp = dir ? cu : cb;
            const int* oix = dir ? src : dst;
#pragma unroll
            for (int i = 0; i < 4; ++i) {
                int r = rb + lk * 4 + i;
                if (r < E_) {
                    const int o = oix[r];
                    float* bp = outp + (size_t)o * 64 + lr;
#pragma unroll
                    for (int n = 0; n < 4; ++n)
                        unsafeAtomicAdd(bp + 16 * n, a2[n][i]);
                }
            }
        }
    }
}

// ---------------- conv buffer init: conv = 1.1*h ----------------------------
__global__ void scale_kernel(const float* __restrict__ h, float* __restrict__ c, int n4)
{
    const int st = gridDim.x * blockDim.x;
    for (int j = blockIdx.x * blockDim.x + threadIdx.x; j < n4; j += st) {
        f32x4 v = ((const f32x4*)h)[j];
        v[0] *= 1.1f; v[1] *= 1.1f; v[2] *= 1.1f; v[3] *= 1.1f;
        ((f32x4*)c)[j] = v;
    }
}

// ---------------- update: h = relu(h+conv) or h = conv; also bf16 mirror ----
__global__ void update_kernel(float* __restrict__ h, const float* __restrict__ c,
                              u16* __restrict__ hbf, int n4, int relu_res)
{
    const int st = gridDim.x * blockDim.x;
    for (int j = blockIdx.x * blockDim.x + threadIdx.x; j < n4; j += st) {
        f32x4 hv = ((const f32x4*)h)[j];
        f32x4 cv = ((const f32x4*)c)[j];
        if (relu_res) {
            hv[0] = fmaxf(hv[0] + cv[0], 0.f); hv[1] = fmaxf(hv[1] + cv[1], 0.f);
            hv[2] = fmaxf(hv[2] + cv[2], 0.f); hv[3] = fmaxf(hv[3] + cv[3], 0.f);
        } else {
            hv = cv;
        }
        ((f32x4*)h)[j] = hv;
        u16x4 p;
        p[0] = f2bf(hv[0]); p[1] = f2bf(hv[1]); p[2] = f2bf(hv[2]); p[3] = f2bf(hv[3]);
        ((u16x4*)hbf)[j] = p;
    }
}

// ---------------- classifier ------------------------------------------------
__global__ __launch_bounds__(512) void cls_mfma(
    const u16* __restrict__ hub, const u16* __restrict__ hbb,
    const int* __restrict__ i0, const int* __restrict__ i1, int EL_,
    const u16* __restrict__ W1, const float* __restrict__ b1,
    const float* __restrict__ W2, const float* __restrict__ b2,
    float* __restrict__ out)
{
    __shared__ u16 sW1[64 * 136];
    const int tid = threadIdx.x;
    const int wv = tid >> 6, lane = tid & 63;
    const int lr = lane & 15, lk = lane >> 4;
    for (int c = tid; c < 1024; c += 512) {
        int row = c >> 4, cc = c & 15;
        *(bf16x8*)&sW1[row * 136 + cc * 8] = *(const bf16x8*)&W1[row * 128 + cc * 8];
    }
    float b1v[4], w2v[4];
#pragma unroll
    for (int n = 0; n < 4; ++n) { b1v[n] = b1[lr + 16 * n]; w2v[n] = W2[lr + 16 * n]; }
    const float b2s = b2[0];
    __syncthreads();

    const int nT = (EL_ + 127) >> 7;
    for (int t = blockIdx.x; t < nT; t += gridDim.x) {
        const int rb = t * 128 + wv * 16;
        int ar = rb + lr; if (ar >= EL_) ar = EL_ - 1;
        const int gu = i0[ar], gb = i1[ar];
        bf16x8 af[4];
        af[0] = *(const bf16x8*)&hub[(size_t)gu * 64 + lk * 8];
        af[1] = *(const bf16x8*)&hub[(size_t)gu * 64 + 32 + lk * 8];
        af[2] = *(const bf16x8*)&hbb[(size_t)gb * 64 + lk * 8];
        af[3] = *(const bf16x8*)&hbb[(size_t)gb * 64 + 32 + lk * 8];
        f32x4 acc[4];
#pragma unroll
        for (int n = 0; n < 4; ++n) acc[n] = (f32x4){b1v[n], b1v[n], b1v[n], b1v[n]};
#pragma unroll
        for (int ks = 0; ks < 4; ++ks) {
#pragma unroll
            for (int n = 0; n < 4; ++n) {
                bf16x8 bfr = *(const bf16x8*)&sW1[(lr + 16 * n) * 136 + ks * 32 + lk * 8];
                acc[n] = __builtin_amdgcn_mfma_f32_16x16x32_bf16(af[ks], bfr, acc[n], 0, 0, 0);
            }
        }
#pragma unroll
        for (int i = 0; i < 4; ++i) {
            float v = 0.f;
#pragma unroll
            for (int n = 0; n < 4; ++n) v = fmaf(fmaxf(acc[n][i], 0.f), w2v[n], v);
            v += __shfl_xor(v, 1); v += __shfl_xor(v, 2);
            v += __shfl_xor(v, 4); v += __shfl_xor(v, 8);
            int r = rb + lk * 4 + i;
            if (lr == 0 && r < EL_) out[r] = v + b2s;
        }
    }
}

extern "C" void kernel_launch(void* const* d_in, const int* in_sizes, int n_in,
                              void* d_out, int out_size, void* d_ws, size_t ws_size,
                              hipStream_t stream)
{
    const float* emb_user = (const float*)d_in[0];
    const float* emb_book = (const float*)d_in[1];
    const float* nu_W1 = (const float*)d_in[2];
    const float* nu_b1 = (const float*)d_in[3];
    const float* nu_W2 = (const float*)d_in[4];
    const float* nu_b2 = (const float*)d_in[5];
    const float* nb_W1 = (const float*)d_in[6];
    const float* nb_b1 = (const float*)d_in[7];
    const float* nb_W2 = (const float*)d_in[8];
    const float* nb_b2 = (const float*)d_in[9];
    const float* eu_W1 = (const float*)d_in[10];
    const float* eu_b1 = (const float*)d_in[11];
    const float* eu_W2 = (const float*)d_in[12];
    const float* eu_b2 = (const float*)d_in[13];
    const float* eb_W1 = (const float*)d_in[14];
    const float* eb_b1 = (const float*)d_in[15];
    const float* eb_W2 = (const float*)d_in[16];
    const float* eb_b2 = (const float*)d_in[17];
    const float* cu2b_W1 = (const float*)d_in[18];
    const float* cu2b_b1 = (const float*)d_in[19];
    const float* cu2b_W2 = (const float*)d_in[20];
    const float* cu2b_b2 = (const float*)d_in[21];
    const float* cb2u_W1 = (const float*)d_in[22];
    const float* cb2u_b1 = (const float*)d_in[23];
    const float* cb2u_W2 = (const float*)d_in[24];
    const float* cb2u_b2 = (const float*)d_in[25];
    const float* cls_W1 = (const float*)d_in[26];
    const float* cls_b1 = (const float*)d_in[27];
    const float* cls_W2 = (const float*)d_in[28];
    const float* cls_b2 = (const float*)d_in[29];
    const float* edge_attr = (const float*)d_in[30];
    const int* n_id_user = (const int*)d_in[31];
    const int* n_id_book = (const int*)d_in[32];
    const int* edge_index = (const int*)d_in[33];
    const int* edge_label_index = (const int*)d_in[34];

    const int NU = in_sizes[31];
    const int NB = in_sizes[32];
    const int E  = in_sizes[33] / 2;
    const int EL = in_sizes[34] / 2;

    const int* src = edge_index;
    const int* dst = edge_index + E;
    const int* li0 = edge_label_index;
    const int* li1 = edge_label_index + EL;

    // workspace layout
    float* hu_f = (float*)d_ws;
    float* hb_f = hu_f + (size_t)NU * 64;
    float* cu   = hb_f + (size_t)NB * 64;
    float* cb   = cu + (size_t)NU * 64;
    u16* hu_b = (u16*)(cb + (size_t)NB * 64);
    u16* hb_b = hu_b + (size_t)NU * 64;
    u16* eu_b = hb_b + (size_t)NB * 64;
    u16* eb_b = eu_b + (size_t)E * 64;
    u16* pool = eb_b + (size_t)E * 64;

    // ---- weight prep ----
    PrepArgs pa;
    const float* srcs[NMAT] = { nu_W1, nu_W2, nb_W1, nb_W2, eu_W1, eu_W2, eb_W1, eb_W2,
        cu2b_W1, cu2b_W1 + 192 * 64, cu2b_W2, cu2b_W2 + 64 * 64,
        cb2u_W1, cb2u_W1 + 192 * 64, cb2u_W2, cb2u_W2 + 64 * 64, cls_W1 };
    const int Ks[NMAT] = {64,64,64,64, 256,64,256,64, 192,192,64,64, 192,192,64,64, 128};
    int offs[NMAT]; int off = 0;
    for (int m = 0; m < NMAT; ++m) { offs[m] = off; off += Ks[m] * 64; }
    for (int m = 0; m < NMAT; ++m) { pa.src[m] = srcs[m]; pa.dstoff[m] = offs[m]; pa.K[m] = Ks[m]; }
    prep_weights<<<NMAT * 64, 256, 0, stream>>>(pa, pool);

    const u16* p_nuW1 = pool + offs[0]; const u16* p_nuW2 = pool + offs[1];
    const u16* p_nbW1 = pool + offs[2]; const u16* p_nbW2 = pool + offs[3];
    const u16* p_euW1 = pool + offs[4]; const u16* p_euW2 = pool + offs[5];
    const u16* p_ebW1 = pool + offs[6]; const u16* p_ebW2 = pool + offs[7];
    const u16* p_u2bW1[2] = { pool + offs[8],  pool + offs[9]  };
    const u16* p_u2bW2[2] = { pool + offs[10], pool + offs[11] };
    const u16* p_b2uW1[2] = { pool + offs[12], pool + offs[13] };
    const u16* p_b2uW2[2] = { pool + offs[14], pool + offs[15] };
    const u16* p_clsW1 = pool + offs[16];

    // ---- node + edge init ----
    node_init_mfma<<<(NU + 127) / 128, 512, 0, stream>>>(emb_user, n_id_user, NU,
        p_nuW1, nu_b1, p_nuW2, nu_b2, hu_f, hu_b);
    node_init_mfma<<<(NB + 127) / 128, 512, 0, stream>>>(emb_book, n_id_book, NB,
        p_nbW1, nb_b1, p_nbW2, nb_b2, hb_f, hb_b);
    edge_init_fused<<<(E + 127) / 128, 512, 0, stream>>>(edge_attr, E,
        p_euW1, eu_b1, p_euW2, eu_b2, p_ebW1, eb_b1, p_ebW2, eb_b2, eu_b, eb_b);

    // ---- conv layers ----
    for (int l = 0; l < 2; ++l) {
        scale_kernel<<<1024, 256, 0, stream>>>(hu_f, cu, NU * 16);
        scale_kernel<<<1024, 256, 0, stream>>>(hb_f, cb, NB * 16);
        edge_msg_fused<<<(E + 127) / 128, 512, 0, stream>>>(hu_b, hb_b, src, dst,
            eu_b, eb_b, E,
            p_u2bW1[l], cu2b_b1 + l * 64, p_u2bW2[l], cu2b_b2 + l * 64,
            p_b2uW1[l], cb2u_b1 + l * 64, p_b2uW2[l], cb2u_b2 + l * 64,
            cb, cu);
        update_kernel<<<1024, 256, 0, stream>>>(hu_f, cu, hu_b, NU * 16, l == 0 ? 1 : 0);
        update_kernel<<<1024, 256, 0, stream>>>(hb_f, cb, hb_b, NB * 16, l == 0 ? 1 : 0);
    }

    // ---- classifier ----
    cls_mfma<<<(EL + 127) / 128, 512, 0, stream>>>(hu_b, hb_b, li0, li1, EL,
        p_clsW1, cls_b1, cls_W2, cls_b2, (float*)d_out);
}

// Round 7
// 571.660 us; speedup vs baseline: 6.4725x; 1.0109x over previous
//
#include <hip/hip_runtime.h>

typedef unsigned short u16;
typedef __attribute__((ext_vector_type(8))) short bf16x8;
typedef __attribute__((ext_vector_type(4))) float f32x4;
typedef __attribute__((ext_vector_type(4))) unsigned short u16x4;

#define NMAT 17

__device__ __forceinline__ u16 f2bf(float f) {
    union { float f; unsigned u; } a; a.f = f;
    unsigned u = a.u;
    return (u16)((u + (((u >> 16) & 1u) + 0x7fffu)) >> 16);
}

// ---------------- weight prep: W[K][64] f32 -> Wt[64][K] bf16 ----------------
struct PrepArgs { const float* src[NMAT]; int dstoff[NMAT]; int K[NMAT]; };

__global__ __launch_bounds__(256) void prep_weights(PrepArgs a, u16* __restrict__ pool) {
    int m = blockIdx.x >> 6;
    int idx = (blockIdx.x & 63) * 256 + threadIdx.x;
    int K = a.K[m];
    if (idx < K * 64) {
        int col = idx / K, k = idx - col * K;
        pool[a.dstoff[m] + idx] = f2bf(a.src[m][(size_t)k * 64 + col]);
    }
}

// ---------------- node init: h = mlp2(emb[nid]) ; out f32 + bf16 ------------
__global__ __launch_bounds__(512) void node_init_mfma(
    const float* __restrict__ emb, const int* __restrict__ nid, int N,
    const u16* __restrict__ W1, const float* __restrict__ b1,
    const u16* __restrict__ W2, const float* __restrict__ b2,
    float* __restrict__ hf, u16* __restrict__ hbf)
{
    __shared__ u16 sW1[64 * 72], sW2[64 * 72], sHid[128 * 72];
    const int tid = threadIdx.x;
    const int wv = tid >> 6, lane = tid & 63;
    const int lr = lane & 15, lk = lane >> 4;

    for (int c = tid; c < 512; c += 512) {
        int row = c >> 3, cc = c & 7;
        *(bf16x8*)&sW1[row * 72 + cc * 8] = *(const bf16x8*)&W1[row * 64 + cc * 8];
        *(bf16x8*)&sW2[row * 72 + cc * 8] = *(const bf16x8*)&W2[row * 64 + cc * 8];
    }
    float b1v[4], b2v[4];
#pragma unroll
    for (int n = 0; n < 4; ++n) { b1v[n] = b1[lr + 16 * n]; b2v[n] = b2[lr + 16 * n]; }

    const int nT = (N + 127) >> 7;
    for (int t = blockIdx.x; t < nT; t += gridDim.x) {
        const int rb = t * 128 + wv * 16;
        int ar = rb + lr; if (ar >= N) ar = N - 1;
        const int g = nid[ar];
        const float* ap = emb + (size_t)g * 64 + lk * 8;
        bf16x8 afr[2];
#pragma unroll
        for (int ks = 0; ks < 2; ++ks) {
            f32x4 lo = *(const f32x4*)(ap + ks * 32);
            f32x4 hi = *(const f32x4*)(ap + ks * 32 + 4);
            bf16x8 v;
            v[0] = (short)f2bf(lo[0]); v[1] = (short)f2bf(lo[1]);
            v[2] = (short)f2bf(lo[2]); v[3] = (short)f2bf(lo[3]);
            v[4] = (short)f2bf(hi[0]); v[5] = (short)f2bf(hi[1]);
            v[6] = (short)f2bf(hi[2]); v[7] = (short)f2bf(hi[3]);
            afr[ks] = v;
        }
        __syncthreads();
        f32x4 acc[4];
#pragma unroll
        for (int n = 0; n < 4; ++n) acc[n] = (f32x4){b1v[n], b1v[n], b1v[n], b1v[n]};
#pragma unroll
        for (int ks = 0; ks < 2; ++ks) {
#pragma unroll
            for (int n = 0; n < 4; ++n) {
                bf16x8 bfr = *(const bf16x8*)&sW1[(lr + 16 * n) * 72 + ks * 32 + lk * 8];
                acc[n] = __builtin_amdgcn_mfma_f32_16x16x32_bf16(afr[ks], bfr, acc[n], 0, 0, 0);
            }
        }
#pragma unroll
        for (int n = 0; n < 4; ++n)
#pragma unroll
            for (int i = 0; i < 4; ++i)
                sHid[(wv * 16 + lk * 4 + i) * 72 + lr + 16 * n] = f2bf(fmaxf(acc[n][i], 0.f));
        __syncthreads();
        f32x4 a2[4];
#pragma unroll
        for (int n = 0; n < 4; ++n) a2[n] = (f32x4){b2v[n], b2v[n], b2v[n], b2v[n]};
#pragma unroll
        for (int ks = 0; ks < 2; ++ks) {
            bf16x8 af = *(const bf16x8*)&sHid[(wv * 16 + lr) * 72 + ks * 32 + lk * 8];
#pragma unroll
            for (int n = 0; n < 4; ++n) {
                bf16x8 bfr = *(const bf16x8*)&sW2[(lr + 16 * n) * 72 + ks * 32 + lk * 8];
                a2[n] = __builtin_amdgcn_mfma_f32_16x16x32_bf16(af, bfr, a2[n], 0, 0, 0);
            }
        }
#pragma unroll
        for (int i = 0; i < 4; ++i) {
            int r = rb + lk * 4 + i;
            if (r < N) {
#pragma unroll
                for (int n = 0; n < 4; ++n) {
                    hf[(size_t)r * 64 + lr + 16 * n] = a2[n][i];
                    hbf[(size_t)r * 64 + lr + 16 * n] = f2bf(a2[n][i]);
                }
            }
        }
    }
}

// -------- fused edge init: eu = mlp2_u(attr), eb = mlp2_b(attr), attr read once
__global__ __launch_bounds__(512) void edge_init_fused(
    const float* __restrict__ attr, int E_,
    const u16* __restrict__ W1u, const float* __restrict__ b1u,
    const u16* __restrict__ W2u, const float* __restrict__ b2u,
    const u16* __restrict__ W1b, const float* __restrict__ b1b,
    const u16* __restrict__ W2b, const float* __restrict__ b2b,
    u16* __restrict__ eu, u16* __restrict__ eb)
{
    __shared__ u16 sW1[64 * 264];
    __shared__ u16 sW2[2][64 * 72];
    __shared__ u16 sHid[128 * 72];
    const int tid = threadIdx.x;
    const int wv = tid >> 6, lane = tid & 63;
    const int lr = lane & 15, lk = lane >> 4;

    for (int c = tid; c < 512; c += 512) {
        int row = c >> 3, cc = c & 7;
        *(bf16x8*)&sW2[0][row * 72 + cc * 8] = *(const bf16x8*)&W2u[row * 64 + cc * 8];
        *(bf16x8*)&sW2[1][row * 72 + cc * 8] = *(const bf16x8*)&W2b[row * 64 + cc * 8];
    }
    float b1v[2][4], b2v[2][4];
#pragma unroll
    for (int n = 0; n < 4; ++n) {
        b1v[0][n] = b1u[lr + 16 * n]; b1v[1][n] = b1b[lr + 16 * n];
        b2v[0][n] = b2u[lr + 16 * n]; b2v[1][n] = b2b[lr + 16 * n];
    }

    const int nT = (E_ + 127) >> 7;
    for (int t = blockIdx.x; t < nT; t += gridDim.x) {
        const int rb = t * 128 + wv * 16;
        int ar = rb + lr; if (ar >= E_) ar = E_ - 1;
        const float* ap = attr + (size_t)ar * 256 + lk * 8;
        bf16x8 afr[8];
#pragma unroll
        for (int ks = 0; ks < 8; ++ks) {
            f32x4 lo = *(const f32x4*)(ap + ks * 32);
            f32x4 hi = *(const f32x4*)(ap + ks * 32 + 4);
            bf16x8 v;
            v[0] = (short)f2bf(lo[0]); v[1] = (short)f2bf(lo[1]);
            v[2] = (short)f2bf(lo[2]); v[3] = (short)f2bf(lo[3]);
            v[4] = (short)f2bf(hi[0]); v[5] = (short)f2bf(hi[1]);
            v[6] = (short)f2bf(hi[2]); v[7] = (short)f2bf(hi[3]);
            afr[ks] = v;
        }
#pragma unroll
        for (int dir = 0; dir < 2; ++dir) {
            __syncthreads();
            const u16* w1g = dir ? W1b : W1u;
            for (int c = tid; c < 2048; c += 512) {
                int row = c >> 5, cc = c & 31;
                *(bf16x8*)&sW1[row * 264 + cc * 8] = *(const bf16x8*)&w1g[row * 256 + cc * 8];
            }
            __syncthreads();
            f32x4 acc[4];
#pragma unroll
            for (int n = 0; n < 4; ++n) acc[n] = (f32x4){b1v[dir][n], b1v[dir][n], b1v[dir][n], b1v[dir][n]};
#pragma unroll
            for (int ks = 0; ks < 8; ++ks) {
#pragma unroll
                for (int n = 0; n < 4; ++n) {
                    bf16x8 bfr = *(const bf16x8*)&sW1[(lr + 16 * n) * 264 + ks * 32 + lk * 8];
                    acc[n] = __builtin_amdgcn_mfma_f32_16x16x32_bf16(afr[ks], bfr, acc[n], 0, 0, 0);
                }
            }
#pragma unroll
            for (int n = 0; n < 4; ++n)
#pragma unroll
                for (int i = 0; i < 4; ++i)
                    sHid[(wv * 16 + lk * 4 + i) * 72 + lr + 16 * n] = f2bf(fmaxf(acc[n][i], 0.f));
            __syncthreads();
            f32x4 a2[4];
#pragma unroll
            for (int n = 0; n < 4; ++n) a2[n] = (f32x4){b2v[dir][n], b2v[dir][n], b2v[dir][n], b2v[dir][n]};
#pragma unroll
            for (int ks = 0; ks < 2; ++ks) {
                bf16x8 af = *(const bf16x8*)&sHid[(wv * 16 + lr) * 72 + ks * 32 + lk * 8];
#pragma unroll
                for (int n = 0; n < 4; ++n) {
                    bf16x8 bfr = *(const bf16x8*)&sW2[dir][(lr + 16 * n) * 72 + ks * 32 + lk * 8];
                    a2[n] = __builtin_amdgcn_mfma_f32_16x16x32_bf16(af, bfr, a2[n], 0, 0, 0);
                }
            }
            u16* op = dir ? eb : eu;
#pragma unroll
            for (int i = 0; i < 4; ++i) {
                int r = rb + lk * 4 + i;
                if (r < E_) {
#pragma unroll
                    for (int n = 0; n < 4; ++n)
                        op[(size_t)r * 64 + lr + 16 * n] = f2bf(a2[n][i]);
                }
            }
        }
    }
}

// -------- fused edge messages (both directions), atomic scatter-add ---------
// 256 threads (4 waves), 64-row tile, LDS 53.2 KB -> 3 blocks/CU.
__global__ __launch_bounds__(256, 3) void edge_msg_fused(
    const u16* __restrict__ hub, const u16* __restrict__ hbb,
    const int* __restrict__ src, const int* __restrict__ dst,
    const u16* __restrict__ eu, const u16* __restrict__ eb, int E_,
    const u16* __restrict__ W1a, const float* __restrict__ b1a,
    const u16* __restrict__ W2a, const float* __restrict__ b2a,
    const u16* __restrict__ W1b, const float* __restrict__ b1b,
    const u16* __restrict__ W2b, const float* __restrict__ b2b,
    float* __restrict__ cb, float* __restrict__ cu)
{
    __shared__ u16 sW1[64 * 200];     // 25.6 KB
    __shared__ u16 sW2[2][64 * 72];   // 18.4 KB
    __shared__ u16 sHid[64 * 72];     // 9.2 KB
    const int tid = threadIdx.x;
    const int wv = tid >> 6, lane = tid & 63;
    const int lr = lane & 15, lk = lane >> 4;

    for (int c = tid; c < 512; c += 256) {
        int row = c >> 3, cc = c & 7;
        *(bf16x8*)&sW2[0][row * 72 + cc * 8] = *(const bf16x8*)&W2a[row * 64 + cc * 8];
        *(bf16x8*)&sW2[1][row * 72 + cc * 8] = *(const bf16x8*)&W2b[row * 64 + cc * 8];
    }

    const int nT = (E_ + 63) >> 6;
    for (int t = blockIdx.x; t < nT; t += gridDim.x) {
        const int rb = t * 64 + wv * 16;
        int ar = rb + lr; if (ar >= E_) ar = E_ - 1;
        const int is = src[ar], id = dst[ar];
        bf16x8 fb[2], fu[2];
#pragma unroll
        for (int ks = 0; ks < 2; ++ks) {
            fb[ks] = *(const bf16x8*)&hbb[(size_t)id * 64 + ks * 32 + lk * 8];
            fu[ks] = *(const bf16x8*)&hub[(size_t)is * 64 + ks * 32 + lk * 8];
        }
#pragma unroll
        for (int dir = 0; dir < 2; ++dir) {
            __syncthreads();   // prev use of sW1/sHid complete
            // per-dir edge-feature gather (overlaps with W1 staging below)
            const u16* ep = dir ? eb : eu;
            bf16x8 fe[2];
            fe[0] = *(const bf16x8*)&ep[(size_t)ar * 64 + lk * 8];
            fe[1] = *(const bf16x8*)&ep[(size_t)ar * 64 + 32 + lk * 8];
            const u16* w1g = dir ? W1b : W1a;
            for (int c = tid; c < 1536; c += 256) {
                int row = c / 24, cc = c - row * 24;
                *(bf16x8*)&sW1[row * 200 + cc * 8] = *(const bf16x8*)&w1g[row * 192 + cc * 8];
            }
            const float* b1p = dir ? b1b : b1a;
            const float* b2p = dir ? b2b : b2a;
            float b1v[4], b2v[4];
#pragma unroll
            for (int n = 0; n < 4; ++n) { b1v[n] = b1p[lr + 16 * n]; b2v[n] = b2p[lr + 16 * n]; }
            __syncthreads();
            bf16x8 aseq[6];
            if (dir == 0) { aseq[0]=fb[0]; aseq[1]=fb[1]; aseq[2]=fu[0]; aseq[3]=fu[1]; }
            else          { aseq[0]=fu[0]; aseq[1]=fu[1]; aseq[2]=fb[0]; aseq[3]=fb[1]; }
            aseq[4]=fe[0]; aseq[5]=fe[1];
            f32x4 acc[4];
#pragma unroll
            for (int n = 0; n < 4; ++n) acc[n] = (f32x4){b1v[n], b1v[n], b1v[n], b1v[n]};
#pragma unroll
            for (int ks = 0; ks < 6; ++ks) {
#pragma unroll
                for (int n = 0; n < 4; ++n) {
                    bf16x8 bfr = *(const bf16x8*)&sW1[(lr + 16 * n) * 200 + ks * 32 + lk * 8];
                    acc[n] = __builtin_amdgcn_mfma_f32_16x16x32_bf16(aseq[ks], bfr, acc[n], 0, 0, 0);
                }
            }
#pragma unroll
            for (int n = 0; n < 4; ++n)
#pragma unroll
                for (int i = 0; i < 4; ++i)
                    sHid[(wv * 16 + lk * 4 + i) * 72 + lr + 16 * n] = f2bf(fmaxf(acc[n][i], 0.f));
            __syncthreads();
            f32x4 a2[4];
#pragma unroll
            for (int n = 0; n < 4; ++n) a2[n] = (f32x4){b2v[n], b2v[n], b2v[n], b2v[n]};
#pragma unroll
            for (int ks = 0; ks < 2; ++ks) {
                bf16x8 af = *(const bf16x8*)&sHid[(wv * 16 + lr) * 72 + ks * 32 + lk * 8];
#pragma unroll
                for (int n = 0; n < 4; ++n) {
                    bf16x8 bfr = *(const bf16x8*)&sW2[dir][(lr + 16 * n) * 72 + ks * 32 + lk * 8];
                    a2[n] = __builtin_amdgcn_mfma_f32_16x16x32_bf16(af, bfr, a2[n], 0, 0, 0);
                }
            }
            float* outp = dir ? cu : cb;
            const int* oix = dir ? src : dst;
#pragma unroll
            for (int i = 0; i < 4; ++i) {
                int r = rb + lk * 4 + i;
                if (r < E_) {
                    const int o = oix[r];
                    float* bp = outp + (size_t)o * 64 + lr;
#pragma unroll
                    for (int n = 0; n < 4; ++n)
                        unsafeAtomicAdd(bp + 16 * n, a2[n][i]);
                }
            }
        }
    }
}

// ---------------- zero conv accumulators ------------------------------------
__global__ void zero_kernel(float* __restrict__ c, int n4)
{
    const int st = gridDim.x * blockDim.x;
    const f32x4 z = (f32x4){0.f, 0.f, 0.f, 0.f};
    for (int j = blockIdx.x * blockDim.x + threadIdx.x; j < n4; j += st)
        ((f32x4*)c)[j] = z;
}

// ------- update (both node types fused; conv holds scatter-sum only) --------
// l==0: h = relu(2.1*h + c), write h + bf16 mirror
// l==1: v = 1.1*h + c, write bf16 mirror only (f32 h is dead afterwards)
__global__ void update_kernel(float* __restrict__ h, const float* __restrict__ c,
                              u16* __restrict__ hbf, int n4, int relu_res)
{
    const int st = gridDim.x * blockDim.x;
    for (int j = blockIdx.x * blockDim.x + threadIdx.x; j < n4; j += st) {
        f32x4 hv = ((const f32x4*)h)[j];
        f32x4 cv = ((const f32x4*)c)[j];
        f32x4 v;
        if (relu_res) {
            v[0] = fmaxf(fmaf(hv[0], 2.1f, cv[0]), 0.f);
            v[1] = fmaxf(fmaf(hv[1], 2.1f, cv[1]), 0.f);
            v[2] = fmaxf(fmaf(hv[2], 2.1f, cv[2]), 0.f);
            v[3] = fmaxf(fmaf(hv[3], 2.1f, cv[3]), 0.f);
            ((f32x4*)h)[j] = v;
        } else {
            v[0] = fmaf(hv[0], 1.1f, cv[0]);
            v[1] = fmaf(hv[1], 1.1f, cv[1]);
            v[2] = fmaf(hv[2], 1.1f, cv[2]);
            v[3] = fmaf(hv[3], 1.1f, cv[3]);
        }
        u16x4 p;
        p[0] = f2bf(v[0]); p[1] = f2bf(v[1]); p[2] = f2bf(v[2]); p[3] = f2bf(v[3]);
        ((u16x4*)hbf)[j] = p;
    }
}

// ---------------- classifier ------------------------------------------------
__global__ __launch_bounds__(512) void cls_mfma(
    const u16* __restrict__ hub, const u16* __restrict__ hbb,
    const int* __restrict__ i0, const int* __restrict__ i1, int EL_,
    const u16* __restrict__ W1, const float* __restrict__ b1,
    const float* __restrict__ W2, const float* __restrict__ b2,
    float* __restrict__ out)
{
    __shared__ u16 sW1[64 * 136];
    const int tid = threadIdx.x;
    const int wv = tid >> 6, lane = tid & 63;
    const int lr = lane & 15, lk = lane >> 4;
    for (int c = tid; c < 1024; c += 512) {
        int row = c >> 4, cc = c & 15;
        *(bf16x8*)&sW1[row * 136 + cc * 8] = *(const bf16x8*)&W1[row * 128 + cc * 8];
    }
    float b1v[4], w2v[4];
#pragma unroll
    for (int n = 0; n < 4; ++n) { b1v[n] = b1[lr + 16 * n]; w2v[n] = W2[lr + 16 * n]; }
    const float b2s = b2[0];
    __syncthreads();

    const int nT = (EL_ + 127) >> 7;
    for (int t = blockIdx.x; t < nT; t += gridDim.x) {
        const int rb = t * 128 + wv * 16;
        int ar = rb + lr; if (ar >= EL_) ar = EL_ - 1;
        const int gu = i0[ar], gb = i1[ar];
        bf16x8 af[4];
        af[0] = *(const bf16x8*)&hub[(size_t)gu * 64 + lk * 8];
        af[1] = *(const bf16x8*)&hub[(size_t)gu * 64 + 32 + lk * 8];
        af[2] = *(const bf16x8*)&hbb[(size_t)gb * 64 + lk * 8];
        af[3] = *(const bf16x8*)&hbb[(size_t)gb * 64 + 32 + lk * 8];
        f32x4 acc[4];
#pragma unroll
        for (int n = 0; n < 4; ++n) acc[n] = (f32x4){b1v[n], b1v[n], b1v[n], b1v[n]};
#pragma unroll
        for (int ks = 0; ks < 4; ++ks) {
#pragma unroll
            for (int n = 0; n < 4; ++n) {
                bf16x8 bfr = *(const bf16x8*)&sW1[(lr + 16 * n) * 136 + ks * 32 + lk * 8];
                acc[n] = __builtin_amdgcn_mfma_f32_16x16x32_bf16(af[ks], bfr, acc[n], 0, 0, 0);
            }
        }
#pragma unroll
        for (int i = 0; i < 4; ++i) {
            float v = 0.f;
#pragma unroll
            for (int n = 0; n < 4; ++n) v = fmaf(fmaxf(acc[n][i], 0.f), w2v[n], v);
            v += __shfl_xor(v, 1); v += __shfl_xor(v, 2);
            v += __shfl_xor(v, 4); v += __shfl_xor(v, 8);
            int r = rb + lk * 4 + i;
            if (lr == 0 && r < EL_) out[r] = v + b2s;
        }
    }
}

extern "C" void kernel_launch(void* const* d_in, const int* in_sizes, int n_in,
                              void* d_out, int out_size, void* d_ws, size_t ws_size,
                              hipStream_t stream)
{
    const float* emb_user = (const float*)d_in[0];
    const float* emb_book = (const float*)d_in[1];
    const float* nu_W1 = (const float*)d_in[2];
    const float* nu_b1 = (const float*)d_in[3];
    const float* nu_W2 = (const float*)d_in[4];
    const float* nu_b2 = (const float*)d_in[5];
    const float* nb_W1 = (const float*)d_in[6];
    const float* nb_b1 = (const float*)d_in[7];
    const float* nb_W2 = (const float*)d_in[8];
    const float* nb_b2 = (const float*)d_in[9];
    const float* eu_W1 = (const float*)d_in[10];
    const float* eu_b1 = (const float*)d_in[11];
    const float* eu_W2 = (const float*)d_in[12];
    const float* eu_b2 = (const float*)d_in[13];
    const float* eb_W1 = (const float*)d_in[14];
    const float* eb_b1 = (const float*)d_in[15];
    const float* eb_W2 = (const float*)d_in[16];
    const float* eb_b2 = (const float*)d_in[17];
    const float* cu2b_W1 = (const float*)d_in[18];
    const float* cu2b_b1 = (const float*)d_in[19];
    const float* cu2b_W2 = (const float*)d_in[20];
    const float* cu2b_b2 = (const float*)d_in[21];
    const float* cb2u_W1 = (const float*)d_in[22];
    const float* cb2u_b1 = (const float*)d_in[23];
    const float* cb2u_W2 = (const float*)d_in[24];
    const float* cb2u_b2 = (const float*)d_in[25];
    const float* cls_W1 = (const float*)d_in[26];
    const float* cls_b1 = (const float*)d_in[27];
    const float* cls_W2 = (const float*)d_in[28];
    const float* cls_b2 = (const float*)d_in[29];
    const float* edge_attr = (const float*)d_in[30];
    const int* n_id_user = (const int*)d_in[31];
    const int* n_id_book = (const int*)d_in[32];
    const int* edge_index = (const int*)d_in[33];
    const int* edge_label_index = (const int*)d_in[34];

    const int NU = in_sizes[31];
    const int NB = in_sizes[32];
    const int E  = in_sizes[33] / 2;
    const int EL = in_sizes[34] / 2;

    const int* src = edge_index;
    const int* dst = edge_index + E;
    const int* li0 = edge_label_index;
    const int* li1 = edge_label_index + EL;

    // workspace layout (hu_f||hb_f, cu||cb, hu_b||hb_b each contiguous)
    float* hu_f = (float*)d_ws;
    float* hb_f = hu_f + (size_t)NU * 64;
    float* cu   = hb_f + (size_t)NB * 64;
    float* cb   = cu + (size_t)NU * 64;
    u16* hu_b = (u16*)(cb + (size_t)NB * 64);
    u16* hb_b = hu_b + (size_t)NU * 64;
    u16* eu_b = hb_b + (size_t)NB * 64;
    u16* eb_b = eu_b + (size_t)E * 64;
    u16* pool = eb_b + (size_t)E * 64;

    // ---- weight prep ----
    PrepArgs pa;
    const float* srcs[NMAT] = { nu_W1, nu_W2, nb_W1, nb_W2, eu_W1, eu_W2, eb_W1, eb_W2,
        cu2b_W1, cu2b_W1 + 192 * 64, cu2b_W2, cu2b_W2 + 64 * 64,
        cb2u_W1, cb2u_W1 + 192 * 64, cb2u_W2, cb2u_W2 + 64 * 64, cls_W1 };
    const int Ks[NMAT] = {64,64,64,64, 256,64,256,64, 192,192,64,64, 192,192,64,64, 128};
    int offs[NMAT]; int off = 0;
    for (int m = 0; m < NMAT; ++m) { offs[m] = off; off += Ks[m] * 64; }
    for (int m = 0; m < NMAT; ++m) { pa.src[m] = srcs[m]; pa.dstoff[m] = offs[m]; pa.K[m] = Ks[m]; }
    prep_weights<<<NMAT * 64, 256, 0, stream>>>(pa, pool);

    const u16* p_nuW1 = pool + offs[0]; const u16* p_nuW2 = pool + offs[1];
    const u16* p_nbW1 = pool + offs[2]; const u16* p_nbW2 = pool + offs[3];
    const u16* p_euW1 = pool + offs[4]; const u16* p_euW2 = pool + offs[5];
    const u16* p_ebW1 = pool + offs[6]; const u16* p_ebW2 = pool + offs[7];
    const u16* p_u2bW1[2] = { pool + offs[8],  pool + offs[9]  };
    const u16* p_u2bW2[2] = { pool + offs[10], pool + offs[11] };
    const u16* p_b2uW1[2] = { pool + offs[12], pool + offs[13] };
    const u16* p_b2uW2[2] = { pool + offs[14], pool + offs[15] };
    const u16* p_clsW1 = pool + offs[16];

    // ---- node + edge init ----
    node_init_mfma<<<(NU + 127) / 128, 512, 0, stream>>>(emb_user, n_id_user, NU,
        p_nuW1, nu_b1, p_nuW2, nu_b2, hu_f, hu_b);
    node_init_mfma<<<(NB + 127) / 128, 512, 0, stream>>>(emb_book, n_id_book, NB,
        p_nbW1, nb_b1, p_nbW2, nb_b2, hb_f, hb_b);
    edge_init_fused<<<(E + 127) / 128, 512, 0, stream>>>(edge_attr, E,
        p_euW1, eu_b1, p_euW2, eu_b2, p_ebW1, eb_b1, p_ebW2, eb_b2, eu_b, eb_b);

    const int n4 = (NU + NB) * 16;
    // ---- conv layers ----
    for (int l = 0; l < 2; ++l) {
        zero_kernel<<<1024, 256, 0, stream>>>(cu, n4);  // cu||cb contiguous
        edge_msg_fused<<<(E + 63) / 64, 256, 0, stream>>>(hu_b, hb_b, src, dst,
            eu_b, eb_b, E,
            p_u2bW1[l], cu2b_b1 + l * 64, p_u2bW2[l], cu2b_b2 + l * 64,
            p_b2uW1[l], cb2u_b1 + l * 64, p_b2uW2[l], cb2u_b2 + l * 64,
            cb, cu);
        update_kernel<<<1024, 256, 0, stream>>>(hu_f, cu, hu_b, n4, l == 0 ? 1 : 0);
    }

    // ---- classifier ----
    cls_mfma<<<(EL + 127) / 128, 512, 0, stream>>>(hu_b, hb_b, li0, li1, EL,
        p_clsW1, cls_b1, cls_W2, cls_b2, (float*)d_out);
}